// Round 6
// baseline (627.019 us; speedup 1.0000x reference)
//
#include <hip/hip_runtime.h>

// SelfAttnPool: B=32, T=4096, F=512, U=512 (fp32 in/out)
//   scores[b,t] = tanh(x[b,t,:]@W + b) @ V ; a = softmax_T(scores)
//   out[b,f] = sum_t a[b,t]*x[b,t,f]
//
// R5: occupancy attack. Wave tile 32r x 128c (acc = 64 AGPR instead of 128),
// 256-thr blocks (4 waves, 32 rows x 512 cols), 4096 blocks,
// __launch_bounds__(256,4) -> 4 waves/SIMD (was 2). B-frags in cf-pairs to
// cap arch VGPRs. Flash chunk-softmax epilogue kept; partial stored bf16-RNE.
// 3-term bf16 split (hh+lh+hl) on mfma 32x32x16 for fp32-grade scores.

#define XT 4096
#define XF 512
#define XU 512
#define NCHUNK 4096          // 32-row chunks
#define CPB 128              // chunks per batch

typedef __attribute__((ext_vector_type(8))) short short8;
typedef __attribute__((ext_vector_type(16))) float f32x16;

__device__ inline unsigned fbits(float x) { return __builtin_bit_cast(unsigned, x); }

__device__ inline void cvt_hilo(float x, unsigned short &h, unsigned short &l) {
  unsigned u = fbits(x);
  h = (unsigned short)(u >> 16);                       // truncated bf16 hi
  float hf = __builtin_bit_cast(float, u & 0xFFFF0000u);
  float lo = x - hf;                                   // exact residual
  l = (unsigned short)(fbits(lo) >> 16);
}

__device__ inline unsigned short bf16_rne(float v) {
  unsigned u = fbits(v);
  return (unsigned short)((u + 0x7FFFu + ((u >> 16) & 1u)) >> 16);
}

__device__ inline float bf16f(unsigned short h) {
  return __builtin_bit_cast(float, (unsigned)h << 16);
}

__device__ inline float tanh_fast(float z) {
  float e = __expf(2.0f * z);
  return 1.0f - 2.0f * __builtin_amdgcn_rcpf(e + 1.0f);
}

// ---- W pre-conversion: fp32 [512 k][512 n] -> bf16 hi/lo, fragment-ready:
// whi/wlo: [slice s(32)][chunk16B: t(16)*64 + g(2)*32 + l(32)][j(8)]
// element = W[k = s*16 + g*8 + j][n = t*32 + l]
__global__ void wconv_kernel(const float *__restrict__ W,
                             unsigned short *__restrict__ whi,
                             unsigned short *__restrict__ wlo) {
  int t2 = blockIdx.x * 256 + threadIdx.x;  // 32768 threads
  int l = t2 & 31;
  int g = (t2 >> 5) & 1;
  int t = (t2 >> 6) & 15;
  int s = t2 >> 10;
  short8 hv, lv;
#pragma unroll
  for (int j = 0; j < 8; ++j) {
    unsigned short h, lo;
    cvt_hilo(W[(size_t)(s * 16 + g * 8 + j) * XU + t * 32 + l], h, lo);
    hv[j] = (short)h;
    lv[j] = (short)lo;
  }
  size_t off = (size_t)s * 8192 + t * 512 + g * 256 + l * 8;
  *(short8 *)(whi + off) = hv;
  *(short8 *)(wlo + off) = lv;
}

#define MFMA(a, b, c) __builtin_amdgcn_mfma_f32_32x32x16_bf16(a, b, c, 0, 0, 0)

// ---- fused GEMM + tanh + (.@V) + chunk softmax + weighted pooling
// block: 256 thr = 4 waves; tile 32 rows x 512 cols (wave wc owns 128 cols).
__global__ __launch_bounds__(256, 4)
void gemm_scores_kernel(const float *__restrict__ x,
                        const unsigned short *__restrict__ whi,
                        const unsigned short *__restrict__ wlo,
                        const float *__restrict__ bias,
                        const float *__restrict__ V,
                        unsigned short *__restrict__ partial,
                        float *__restrict__ pstats) {
  __shared__ float scb[128];   // [wc(4)][row(32)]
  __shared__ float sarr[32];
  __shared__ float warr[32];
  __shared__ float red[512];

  const int tid = threadIdx.x;
  const int lane = tid & 63;
  const int wc = tid >> 6;     // wave = col quarter
  const int l31 = lane & 31;
  const int half = lane >> 5;
  const size_t rowbase = (size_t)blockIdx.x * 32;

  f32x16 acc[4];
#pragma unroll
  for (int c = 0; c < 4; ++c)
#pragma unroll
    for (int r = 0; r < 16; ++r) acc[c][r] = 0.f;

  // A: row = rowbase + l31 ; k = s*16 + half*8 + j  (shared by all 4 waves)
  const float *xr = x + (rowbase + l31) * XF + half * 8;
  const unsigned short *whp = whi + (size_t)(wc * 4) * 512 + lane * 8;
  const unsigned short *wlp = wlo + (size_t)(wc * 4) * 512 + lane * 8;

#pragma unroll 1
  for (int s = 0; s < 32; ++s) {
    float4 a0 = *(const float4 *)(xr + s * 16);
    float4 a1 = *(const float4 *)(xr + s * 16 + 4);
    short8 ah, al;
    {
      float v[8] = {a0.x, a0.y, a0.z, a0.w, a1.x, a1.y, a1.z, a1.w};
#pragma unroll
      for (int j = 0; j < 8; ++j) {
        unsigned short h, lo;
        cvt_hilo(v[j], h, lo);
        ah[j] = (short)h;
        al[j] = (short)lo;
      }
    }
#pragma unroll
    for (int p = 0; p < 2; ++p) {
      const unsigned short *bp = whp + (size_t)s * 8192 + p * 1024;
      const unsigned short *bq = wlp + (size_t)s * 8192 + p * 1024;
      short8 bh0 = *(const short8 *)(bp);
      short8 bh1 = *(const short8 *)(bp + 512);
      short8 bl0 = *(const short8 *)(bq);
      short8 bl1 = *(const short8 *)(bq + 512);
      acc[2 * p] = MFMA(ah, bh0, acc[2 * p]);
      acc[2 * p + 1] = MFMA(ah, bh1, acc[2 * p + 1]);
      acc[2 * p] = MFMA(al, bh0, acc[2 * p]);
      acc[2 * p + 1] = MFMA(al, bh1, acc[2 * p + 1]);
      acc[2 * p] = MFMA(ah, bl0, acc[2 * p]);
      acc[2 * p + 1] = MFMA(ah, bl1, acc[2 * p + 1]);
    }
  }

  // ---- score epilogue: sc[row] = sum_n tanh(acc + b[n]) * V[n]
  // C/D 32x32: col n = l31 (+32*cf+128*wc); row = (r&3)+8*(r>>2)+4*half
  float sc[16];
#pragma unroll
  for (int r = 0; r < 16; ++r) sc[r] = 0.f;
#pragma unroll
  for (int cf = 0; cf < 4; ++cf) {
    int n = wc * 128 + cf * 32 + l31;
    float vv = V[n];
    float bb = bias[n];
#pragma unroll
    for (int r = 0; r < 16; ++r) sc[r] += tanh_fast(acc[cf][r] + bb) * vv;
  }
#pragma unroll
  for (int m = 1; m <= 16; m <<= 1)
#pragma unroll
    for (int r = 0; r < 16; ++r) sc[r] += __shfl_xor(sc[r], m, 64);
  if (l31 == 0) {
#pragma unroll
    for (int r = 0; r < 16; ++r) {
      int row = (r & 3) + 8 * (r >> 2) + 4 * half;
      scb[wc * 32 + row] = sc[r];
    }
  }
  __syncthreads();

  // ---- chunk-local softmax over 32 rows
  if (tid < 32)
    sarr[tid] = scb[tid] + scb[32 + tid] + scb[64 + tid] + scb[96 + tid];
  __syncthreads();
  float mloc = -1e30f;
#pragma unroll 8
  for (int i = 0; i < 32; ++i) mloc = fmaxf(mloc, sarr[i]);
  if (tid < 32) warr[tid] = __expf(sarr[tid] - mloc);
  __syncthreads();

  // ---- weighted pooling over own (L2-hot) 32x512 tile
  const int rg = tid >> 7;   // 0/1 -> rows rg*16..+16
  const int c4 = tid & 127;  // float4 column
  const float *xp = x + rowbase * XF;
  float4 pa = {0.f, 0.f, 0.f, 0.f};
#pragma unroll 8
  for (int i = 0; i < 16; ++i) {
    int r = rg * 16 + i;
    float4 v = *(const float4 *)(xp + (size_t)r * XF + c4 * 4);
    float wv = warr[r];
    pa.x += wv * v.x;
    pa.y += wv * v.y;
    pa.z += wv * v.z;
    pa.w += wv * v.w;
  }
  if (rg == 1) {
    float *rp = red + c4 * 4;
    rp[0] = pa.x; rp[1] = pa.y; rp[2] = pa.z; rp[3] = pa.w;
  }
  __syncthreads();
  if (rg == 0) {
    const float *r0 = red + c4 * 4;
    unsigned short o[4];
    o[0] = bf16_rne(pa.x + r0[0]);
    o[1] = bf16_rne(pa.y + r0[1]);
    o[2] = bf16_rne(pa.z + r0[2]);
    o[3] = bf16_rne(pa.w + r0[3]);
    *(uint2 *)(partial + (size_t)blockIdx.x * 512 + c4 * 4) =
        *(const uint2 *)o;
  }
  if (tid == 0) {
    float l = 0.f;
#pragma unroll
    for (int i = 0; i < 32; ++i) l += warr[i];
    pstats[blockIdx.x * 2] = mloc;
    pstats[blockIdx.x * 2 + 1] = l;
  }
}

// ---- combine: out[b,f] = sum_c e^{m_c-M} partial[c][f] / (sum_c e^{m_c-M} l_c)
__global__ __launch_bounds__(512)
void combine_kernel(const unsigned short *__restrict__ partial,
                    const float *__restrict__ pstats,
                    float *__restrict__ out) {
  int b = blockIdx.x;
  int f = threadIdx.x;
  __shared__ float ml[CPB], ll[CPB];
  if (f < CPB) {
    ml[f] = pstats[(b * CPB + f) * 2];
    ll[f] = pstats[(b * CPB + f) * 2 + 1];
  }
  __syncthreads();
  float M = -1e30f;
#pragma unroll 8
  for (int c = 0; c < CPB; ++c) M = fmaxf(M, ml[c]);
  float L = 0.f;
  float acc = 0.f;
#pragma unroll 4
  for (int c = 0; c < CPB; ++c) {
    float e = __expf(ml[c] - M);
    L += e * ll[c];
    acc += e * bf16f(partial[(size_t)(b * CPB + c) * 512 + f]);
  }
  out[b * XF + f] = acc / L;
}

extern "C" void kernel_launch(void *const *d_in, const int *in_sizes, int n_in,
                              void *d_out, int out_size, void *d_ws,
                              size_t ws_size, hipStream_t stream) {
  const float *x = (const float *)d_in[0];
  const float *W = (const float *)d_in[1];
  const float *bias = (const float *)d_in[2];
  const float *V = (const float *)d_in[3];
  float *out = (float *)d_out;

  // workspace: whi 512KB | wlo 512KB | partial(bf16) 4MB | pstats 32KB
  unsigned short *whi = (unsigned short *)d_ws;
  unsigned short *wlo = whi + 262144;
  unsigned short *partial = (unsigned short *)((char *)d_ws + 1048576);
  float *pstats = (float *)((char *)d_ws + 1048576 + 4194304);

  wconv_kernel<<<128, 256, 0, stream>>>(W, whi, wlo);
  gemm_scores_kernel<<<NCHUNK, 256, 0, stream>>>(x, whi, wlo, bias, V, partial,
                                                 pstats);
  combine_kernel<<<32, 512, 0, stream>>>(partial, pstats, out);
}